// Round 1
// baseline (697.724 us; speedup 1.0000x reference)
//
#include <hip/hip_runtime.h>
#include <hip/hip_bf16.h>

#define NEG_SLOPE 0.2f

// ---------------- CSR build ----------------

__global__ void k_hist(const int* __restrict__ dst, int* __restrict__ deg, int E) {
    int e = blockIdx.x * blockDim.x + threadIdx.x;
    if (e < E) atomicAdd(&deg[dst[e]], 1);
}

__global__ __launch_bounds__(1024) void k_scan(const int* __restrict__ deg,
                                               int* __restrict__ row_start, int n) {
    __shared__ int sdata[1024];
    int tid = threadIdx.x;
    int per = (n + 1023) / 1024;
    int begin = tid * per;
    int end = begin + per; if (end > n) end = n;
    int sum = 0;
    for (int i = begin; i < end && i < n; i++) sum += deg[i];
    sdata[tid] = sum;
    __syncthreads();
    // Hillis-Steele inclusive scan over 1024 partials
    for (int off = 1; off < 1024; off <<= 1) {
        int t = (tid >= off) ? sdata[tid - off] : 0;
        __syncthreads();
        sdata[tid] += t;
        __syncthreads();
    }
    int run = sdata[tid] - sum;  // exclusive prefix for this thread's chunk
    for (int i = begin; i < end && i < n; i++) { row_start[i] = run; run += deg[i]; }
    if (tid == 1023) row_start[n] = sdata[1023];
}

__global__ void k_scatter(const int* __restrict__ dst, const int* __restrict__ row_start,
                          int* __restrict__ cursor, int* __restrict__ edge_list, int E) {
    int e = blockIdx.x * blockDim.x + threadIdx.x;
    if (e < E) {
        int d = dst[e];
        int pos = row_start[d] + atomicAdd(&cursor[d], 1);
        edge_list[pos] = e;
    }
}

// ---------------- Layer 1 GEMM: z1 = feat @ W1, + el1/er1 ----------------

__global__ __launch_bounds__(256) void k_gemm1(const float* __restrict__ feat,
                                               const float* __restrict__ W1,
                                               const float* __restrict__ al,
                                               const float* __restrict__ ar,
                                               float* __restrict__ z1,
                                               float* __restrict__ el1,
                                               float* __restrict__ er1, int n) {
    __shared__ float sW[960], sal[96], sar[96];
    for (int i = threadIdx.x; i < 960; i += 256) sW[i] = W1[i];
    for (int i = threadIdx.x; i < 96; i += 256) { sal[i] = al[i]; sar[i] = ar[i]; }
    __syncthreads();
    int nd = blockIdx.x * 256 + threadIdx.x;
    if (nd >= n) return;
    float x[10];
#pragma unroll
    for (int k = 0; k < 10; k++) x[k] = feat[(size_t)nd * 10 + k];
#pragma unroll
    for (int h = 0; h < 3; h++) {
        float el = 0.f, er = 0.f;
#pragma unroll
        for (int d = 0; d < 32; d++) {
            int c = h * 32 + d;
            float acc = 0.f;
#pragma unroll
            for (int k = 0; k < 10; k++) acc += x[k] * sW[k * 96 + c];
            z1[(size_t)nd * 96 + c] = acc;
            el += acc * sal[c];
            er += acc * sar[c];
        }
        el1[nd * 3 + h] = el;
        er1[nd * 3 + h] = er;
    }
}

// ---------------- GAT aggregation: wave per dst node ----------------

template <int H, int D>
__global__ __launch_bounds__(256) void k_agg(const float* __restrict__ z,
                                             const float* __restrict__ el,
                                             const float* __restrict__ er,
                                             const int* __restrict__ row_start,
                                             const int* __restrict__ edge_list,
                                             const int* __restrict__ srcv,
                                             float* __restrict__ xout, int n) {
    constexpr int HD = H * D;
    constexpr int NC = (HD + 63) / 64;  // columns per lane
    int wid = (blockIdx.x * blockDim.x + threadIdx.x) >> 6;
    int lane = threadIdx.x & 63;
    if (wid >= n) return;
    int s0 = row_start[wid];
    int deg = row_start[wid + 1] - s0;
    if (deg <= 0) {
#pragma unroll
        for (int j = 0; j < NC; j++) {
            int c = lane + 64 * j;
            if (c < HD) xout[(size_t)wid * HD + c] = 0.f;
        }
        return;
    }
    float ern[H];
#pragma unroll
    for (int h = 0; h < H; h++) ern[h] = er[wid * H + h];

    // pass A1: per-head max over incoming edges
    float m[H];
#pragma unroll
    for (int h = 0; h < H; h++) m[h] = -3.402823466e38f;
    for (int i = lane; i < deg; i += 64) {
        int e = edge_list[s0 + i];
        int sv = srcv[e];
#pragma unroll
        for (int h = 0; h < H; h++) {
            float v = el[sv * H + h] + ern[h];
            v = v > 0.f ? v : NEG_SLOPE * v;
            m[h] = fmaxf(m[h], v);
        }
    }
#pragma unroll
    for (int h = 0; h < H; h++)
        for (int off = 32; off; off >>= 1) m[h] = fmaxf(m[h], __shfl_xor(m[h], off));

    // pass A2: per-head sum of exp
    float s[H];
#pragma unroll
    for (int h = 0; h < H; h++) s[h] = 0.f;
    for (int i = lane; i < deg; i += 64) {
        int e = edge_list[s0 + i];
        int sv = srcv[e];
#pragma unroll
        for (int h = 0; h < H; h++) {
            float v = el[sv * H + h] + ern[h];
            v = v > 0.f ? v : NEG_SLOPE * v;
            s[h] += expf(v - m[h]);
        }
    }
#pragma unroll
    for (int h = 0; h < H; h++)
        for (int off = 32; off; off >>= 1) s[h] += __shfl_xor(s[h], off);
    float inv[H];
#pragma unroll
    for (int h = 0; h < H; h++) inv[h] = 1.f / (s[h] + 1e-16f);

    // pass B: weighted accumulation of z[src] rows
    float acc[NC];
#pragma unroll
    for (int j = 0; j < NC; j++) acc[j] = 0.f;
    for (int i = 0; i < deg; i++) {
        int e = edge_list[s0 + i];
        int sv = srcv[e];
        float a[H];
#pragma unroll
        for (int h = 0; h < H; h++) {
            float v = el[sv * H + h] + ern[h];
            v = v > 0.f ? v : NEG_SLOPE * v;
            a[h] = expf(v - m[h]) * inv[h];
        }
        const float* zr = z + (size_t)sv * HD;
#pragma unroll
        for (int j = 0; j < NC; j++) {
            int c = lane + 64 * j;
            if (c < HD) acc[j] += a[c / D] * zr[c];
        }
    }
#pragma unroll
    for (int j = 0; j < NC; j++) {
        int c = lane + 64 * j;
        if (c < HD) xout[(size_t)wid * HD + c] = fmaxf(acc[j], 0.f);  // fused ReLU
    }
}

// ---------------- Layer 2 GEMM: z2 = x1 @ W2 (50000x96 @ 96x192) ----------------

__global__ __launch_bounds__(256) void k_gemm2(const float* __restrict__ A,
                                               const float* __restrict__ B,
                                               float* __restrict__ C, int M) {
    __shared__ float sA[64][17];
    __shared__ float sB[16][64];
    int t = threadIdx.x;
    int n0 = blockIdx.x * 64;
    int c0 = blockIdx.y * 64;
    int ty = t >> 4, tx = t & 15;
    float acc[4][4] = {};
    for (int k0 = 0; k0 < 96; k0 += 16) {
        int arow = t >> 2, aq = (t & 3) * 4;
        float4 av = make_float4(0.f, 0.f, 0.f, 0.f);
        if (n0 + arow < M)
            av = *reinterpret_cast<const float4*>(&A[(size_t)(n0 + arow) * 96 + k0 + aq]);
        sA[arow][aq + 0] = av.x; sA[arow][aq + 1] = av.y;
        sA[arow][aq + 2] = av.z; sA[arow][aq + 3] = av.w;
        int brow = t >> 4, bq = (t & 15) * 4;
        float4 bv = *reinterpret_cast<const float4*>(&B[(size_t)(k0 + brow) * 192 + c0 + bq]);
        *reinterpret_cast<float4*>(&sB[brow][bq]) = bv;
        __syncthreads();
#pragma unroll
        for (int kk = 0; kk < 16; kk++) {
            float a[4];
#pragma unroll
            for (int i = 0; i < 4; i++) a[i] = sA[ty * 4 + i][kk];
            float4 bb = *reinterpret_cast<const float4*>(&sB[kk][tx * 4]);
            float b[4] = {bb.x, bb.y, bb.z, bb.w};
#pragma unroll
            for (int i = 0; i < 4; i++)
#pragma unroll
                for (int j = 0; j < 4; j++) acc[i][j] += a[i] * b[j];
        }
        __syncthreads();
    }
#pragma unroll
    for (int i = 0; i < 4; i++) {
        int r = n0 + ty * 4 + i;
        if (r < M) {
            float4 o = make_float4(acc[i][0], acc[i][1], acc[i][2], acc[i][3]);
            *reinterpret_cast<float4*>(&C[(size_t)r * 192 + c0 + tx * 4]) = o;
        }
    }
}

// ---------------- el2/er2 from z2 ----------------

__global__ void k_elr2(const float* __restrict__ z2, const float* __restrict__ al,
                       const float* __restrict__ ar, float* __restrict__ el,
                       float* __restrict__ er, int n) {
    int idx = blockIdx.x * blockDim.x + threadIdx.x;
    if (idx >= n * 3) return;
    int nd = idx / 3, h = idx % 3;
    const float* zr = z2 + (size_t)nd * 192 + h * 64;
    float e1 = 0.f, e2 = 0.f;
#pragma unroll
    for (int d = 0; d < 64; d++) {
        float zv = zr[d];
        e1 += zv * al[h * 64 + d];
        e2 += zv * ar[h * 64 + d];
    }
    el[idx] = e1;
    er[idx] = e2;
}

// ---------------- graph mean-pool (graph_ids sorted) ----------------

__global__ __launch_bounds__(192) void k_pool(const float* __restrict__ x2,
                                              const int* __restrict__ gid,
                                              float* __restrict__ gsum,
                                              int* __restrict__ gcnt, int n) {
    int base = blockIdx.x * 128;
    if (base >= n) return;
    int end = base + 128; if (end > n) end = n;
    int c = threadIdx.x;  // 0..191
    float acc = 0.f;
    int gprev = gid[base];
    for (int i = base; i < end; i++) {
        int g = gid[i];
        if (g != gprev) {
            atomicAdd(&gsum[gprev * 192 + c], acc);
            acc = 0.f;
            gprev = g;
        }
        acc += x2[(size_t)i * 192 + c];
    }
    atomicAdd(&gsum[gprev * 192 + c], acc);
    if (c == 0) {
        int cnt = 0;
        gprev = gid[base];
        for (int i = base; i < end; i++) {
            int g = gid[i];
            if (g != gprev) { atomicAdd(&gcnt[gprev], cnt); cnt = 0; gprev = g; }
            cnt++;
        }
        atomicAdd(&gcnt[gprev], cnt);
    }
}

// ---------------- MLP head: one wave per graph ----------------

__global__ __launch_bounds__(64) void k_head(const float* __restrict__ gsum,
                                             const int* __restrict__ gcnt,
                                             const float* __restrict__ d1w,
                                             const float* __restrict__ d1b,
                                             const float* __restrict__ d2w,
                                             const float* __restrict__ d2b,
                                             float* __restrict__ out, int G) {
    int g = blockIdx.x, j = threadIdx.x;
    float inv = 1.f / fmaxf((float)gcnt[g], 1.f);
    float h = d1b[j];
    for (int k = 0; k < 192; k++) h += (gsum[g * 192 + k] * inv) * d1w[(size_t)k * 64 + j];
    h = fmaxf(h, 0.f);
    float v = h * d2w[j];
    for (int off = 32; off; off >>= 1) v += __shfl_xor(v, off);
    if (j == 0) out[g] = v + d2b[0];
}

// ---------------- launch ----------------

extern "C" void kernel_launch(void* const* d_in, const int* in_sizes, int n_in,
                              void* d_out, int out_size, void* d_ws, size_t ws_size,
                              hipStream_t stream) {
    const float* feat = (const float*)d_in[0];
    const int* src = (const int*)d_in[1];
    const int* dst = (const int*)d_in[2];
    const int* gid = (const int*)d_in[3];
    const float* W1 = (const float*)d_in[4];
    const float* al1 = (const float*)d_in[5];
    const float* ar1 = (const float*)d_in[6];
    const float* W2 = (const float*)d_in[7];
    const float* al2 = (const float*)d_in[8];
    const float* ar2 = (const float*)d_in[9];
    const float* d1w = (const float*)d_in[10];
    const float* d1b = (const float*)d_in[11];
    const float* d2w = (const float*)d_in[12];
    const float* d2b = (const float*)d_in[13];
    float* out = (float*)d_out;
    const int N = in_sizes[0] / 10;   // 50000
    const int E = in_sizes[1];        // 800000
    const int G = out_size;           // 128

    char* p = (char*)d_ws;
    auto take = [&](size_t bytes) -> char* {
        char* r = p;
        p += (bytes + 255) & ~(size_t)255;
        return r;
    };
    // region0 holds z1 (N*96) + x1 (N*96); later reused as x2 (N*192).
    float* region0 = (float*)take((size_t)N * 192 * 4);
    float* z1 = region0;
    float* x1 = region0 + (size_t)N * 96;
    float* x2 = region0;
    float* z2 = (float*)take((size_t)N * 192 * 4);
    float* el1 = (float*)take((size_t)N * 3 * 4);
    float* er1 = (float*)take((size_t)N * 3 * 4);
    float* el2 = (float*)take((size_t)N * 3 * 4);
    float* er2 = (float*)take((size_t)N * 3 * 4);
    int* deg = (int*)take((size_t)N * 4);
    int* row_start = (int*)take((size_t)(N + 1) * 4);
    int* cursor = (int*)take((size_t)N * 4);
    int* edge_list = (int*)take((size_t)E * 4);
    float* gsum = (float*)take((size_t)G * 192 * 4);
    int* gcnt = (int*)take((size_t)G * 4);

    hipMemsetAsync(deg, 0, (size_t)N * 4, stream);
    hipMemsetAsync(cursor, 0, (size_t)N * 4, stream);
    hipMemsetAsync(gsum, 0, (size_t)G * 192 * 4, stream);
    hipMemsetAsync(gcnt, 0, (size_t)G * 4, stream);

    // CSR build (bucket edges by dst)
    k_hist<<<(E + 255) / 256, 256, 0, stream>>>(dst, deg, E);
    k_scan<<<1, 1024, 0, stream>>>(deg, row_start, N);
    k_scatter<<<(E + 255) / 256, 256, 0, stream>>>(dst, row_start, cursor, edge_list, E);

    // Layer 1
    k_gemm1<<<(N + 255) / 256, 256, 0, stream>>>(feat, W1, al1, ar1, z1, el1, er1, N);
    k_agg<3, 32><<<((size_t)N * 64 + 255) / 256, 256, 0, stream>>>(z1, el1, er1, row_start,
                                                                   edge_list, src, x1, N);
    // Layer 2
    k_gemm2<<<dim3((N + 63) / 64, 3), 256, 0, stream>>>(x1, W2, z2, N);
    k_elr2<<<(N * 3 + 255) / 256, 256, 0, stream>>>(z2, al2, ar2, el2, er2, N);
    k_agg<3, 64><<<((size_t)N * 64 + 255) / 256, 256, 0, stream>>>(z2, el2, er2, row_start,
                                                                   edge_list, src, x2, N);
    // Pool + head
    k_pool<<<(N + 127) / 128, 192, 0, stream>>>(x2, gid, gsum, gcnt, N);
    k_head<<<G, 64, 0, stream>>>(gsum, gcnt, d1w, d1b, d2w, d2b, out, G);
}

// Round 2
// 515.540 us; speedup vs baseline: 1.3534x; 1.3534x over previous
//
#include <hip/hip_runtime.h>
#include <hip/hip_bf16.h>

#define NEG_SLOPE 0.2f

__device__ __forceinline__ float wave_max64(float v) {
    for (int o = 32; o; o >>= 1) v = fmaxf(v, __shfl_xor(v, o));
    return v;
}
__device__ __forceinline__ float wave_sum64(float v) {
    for (int o = 32; o; o >>= 1) v += __shfl_xor(v, o);
    return v;
}

// ---------------- CSR build ----------------

__global__ void k_hist(const int* __restrict__ dst, int* __restrict__ deg, int E) {
    int e = blockIdx.x * blockDim.x + threadIdx.x;
    if (e < E) atomicAdd(&deg[dst[e]], 1);
}

__global__ __launch_bounds__(1024) void k_scan(const int* __restrict__ deg,
                                               int* __restrict__ row_start, int n) {
    __shared__ int sdata[1024];
    int tid = threadIdx.x;
    int per = (n + 1023) / 1024;
    int begin = tid * per;
    int end = begin + per; if (end > n) end = n;
    int sum = 0;
    for (int i = begin; i < end && i < n; i++) sum += deg[i];
    sdata[tid] = sum;
    __syncthreads();
    for (int off = 1; off < 1024; off <<= 1) {
        int t = (tid >= off) ? sdata[tid - off] : 0;
        __syncthreads();
        sdata[tid] += t;
        __syncthreads();
    }
    int run = sdata[tid] - sum;
    for (int i = begin; i < end && i < n; i++) { row_start[i] = run; run += deg[i]; }
    if (tid == 1023) row_start[n] = sdata[1023];
}

__global__ void k_scatter(const int* __restrict__ dst, const int* __restrict__ row_start,
                          int* __restrict__ cursor, int* __restrict__ edge_list, int E) {
    int e = blockIdx.x * blockDim.x + threadIdx.x;
    if (e < E) {
        int d = dst[e];
        int pos = row_start[d] + atomicAdd(&cursor[d], 1);
        edge_list[pos] = e;
    }
}

// ---------------- Layer 1 GEMM: z1 = feat @ W1, fused el1/er1 (padded float4) ----------------

__global__ __launch_bounds__(256) void k_gemm1(const float* __restrict__ feat,
                                               const float* __restrict__ W1,
                                               const float* __restrict__ al,
                                               const float* __restrict__ ar,
                                               float* __restrict__ z1,
                                               float4* __restrict__ el1,
                                               float4* __restrict__ er1, int n) {
    __shared__ float sW[960], sal[96], sar[96];
    for (int i = threadIdx.x; i < 960; i += 256) sW[i] = W1[i];
    for (int i = threadIdx.x; i < 96; i += 256) { sal[i] = al[i]; sar[i] = ar[i]; }
    __syncthreads();
    int nd = blockIdx.x * 256 + threadIdx.x;
    if (nd >= n) return;
    float x[10];
#pragma unroll
    for (int k = 0; k < 10; k++) x[k] = feat[(size_t)nd * 10 + k];
    float el[3] = {0.f, 0.f, 0.f}, er[3] = {0.f, 0.f, 0.f};
#pragma unroll
    for (int h = 0; h < 3; h++) {
#pragma unroll
        for (int d0 = 0; d0 < 32; d0 += 4) {
            float o[4];
#pragma unroll
            for (int q = 0; q < 4; q++) {
                int c = h * 32 + d0 + q;
                float acc = 0.f;
#pragma unroll
                for (int k = 0; k < 10; k++) acc += x[k] * sW[k * 96 + c];
                o[q] = acc;
                el[h] += acc * sal[c];
                er[h] += acc * sar[c];
            }
            *reinterpret_cast<float4*>(&z1[(size_t)nd * 96 + h * 32 + d0]) =
                make_float4(o[0], o[1], o[2], o[3]);
        }
    }
    el1[nd] = make_float4(el[0], el[1], el[2], 0.f);
    er1[nd] = make_float4(er[0], er[1], er[2], 0.f);
}

// ---------------- GAT aggregation: wave per dst node, single-pass softmax ----------------
// H=3 heads fixed. VW = vector width for pass B (2 for HD=96, 4 for HD=192). NL = HD/VW = 48.

template <int D, int VW>
__global__ __launch_bounds__(256) void k_agg(const float* __restrict__ z,
                                             const float4* __restrict__ el,
                                             const float4* __restrict__ er,
                                             const int* __restrict__ row_start,
                                             const int* __restrict__ edge_list,
                                             const int* __restrict__ srcv,
                                             float* __restrict__ xout, int n) {
    constexpr int H = 3;
    constexpr int HD = H * D;
    constexpr int NL = HD / VW;
    int wid = (blockIdx.x * blockDim.x + threadIdx.x) >> 6;
    int lane = threadIdx.x & 63;
    if (wid >= n) return;
    int s0 = row_start[wid];
    int deg = row_start[wid + 1] - s0;
    float* orow = xout + (size_t)wid * HD;
    if (deg <= 0) {
#pragma unroll
        for (int j = 0; j < (HD + 63) / 64; j++) {
            int c = lane + 64 * j;
            if (c < HD) orow[c] = 0.f;
        }
        return;
    }
    float4 erv = er[wid];
    int hh = (VW * lane) / D;  // head owned by this lane's column chunk
    if (hh >= H) hh = H - 1;

    if (deg <= 64) {
        // ---- lane-parallel softmax: lane i owns edge i ----
        bool act = lane < deg;
        int sv = act ? srcv[edge_list[s0 + lane]] : 0;
        float4 elv = el[sv];
        float v0 = elv.x + erv.x; v0 = v0 > 0.f ? v0 : NEG_SLOPE * v0;
        float v1 = elv.y + erv.y; v1 = v1 > 0.f ? v1 : NEG_SLOPE * v1;
        float v2 = elv.z + erv.z; v2 = v2 > 0.f ? v2 : NEG_SLOPE * v2;
        if (!act) { v0 = -3.402823466e38f; v1 = v0; v2 = v0; }
        float m0 = wave_max64(v0), m1 = wave_max64(v1), m2 = wave_max64(v2);
        float p0 = act ? __expf(v0 - m0) : 0.f;
        float p1 = act ? __expf(v1 - m1) : 0.f;
        float p2 = act ? __expf(v2 - m2) : 0.f;
        float su0 = wave_sum64(p0), su1 = wave_sum64(p1), su2 = wave_sum64(p2);
        float sh = hh == 0 ? su0 : (hh == 1 ? su1 : su2);
        float invh = 1.f / (sh + 1e-16f);
        int zofs = sv * HD;

        int col = VW * (lane < NL ? lane : NL - 1);
        float acc0 = 0.f, acc1 = 0.f, acc2 = 0.f, acc3 = 0.f;
#pragma unroll 2
        for (int i = 0; i < deg; i++) {
            int zo = __shfl(zofs, i);
            float a0 = __shfl(p0, i), a1 = __shfl(p1, i), a2 = __shfl(p2, i);
            float a = hh == 0 ? a0 : (hh == 1 ? a1 : a2);
            const float* zp = z + zo + col;
            if constexpr (VW == 2) {
                float2 zv = *reinterpret_cast<const float2*>(zp);
                acc0 += a * zv.x; acc1 += a * zv.y;
            } else {
                float4 zv = *reinterpret_cast<const float4*>(zp);
                acc0 += a * zv.x; acc1 += a * zv.y;
                acc2 += a * zv.z; acc3 += a * zv.w;
            }
        }
        if (lane < NL) {
            if constexpr (VW == 2) {
                *reinterpret_cast<float2*>(orow + col) =
                    make_float2(fmaxf(acc0 * invh, 0.f), fmaxf(acc1 * invh, 0.f));
            } else {
                *reinterpret_cast<float4*>(orow + col) =
                    make_float4(fmaxf(acc0 * invh, 0.f), fmaxf(acc1 * invh, 0.f),
                                fmaxf(acc2 * invh, 0.f), fmaxf(acc3 * invh, 0.f));
            }
        }
    } else {
        // ---- fallback 3-pass (rare: deg > 64) ----
        float ern[3] = {erv.x, erv.y, erv.z};
        float m[3] = {-3.402823466e38f, -3.402823466e38f, -3.402823466e38f};
        for (int i = lane; i < deg; i += 64) {
            int sv = srcv[edge_list[s0 + i]];
            float4 elv = el[sv];
            float vv[3] = {elv.x, elv.y, elv.z};
#pragma unroll
            for (int h = 0; h < 3; h++) {
                float v = vv[h] + ern[h];
                v = v > 0.f ? v : NEG_SLOPE * v;
                m[h] = fmaxf(m[h], v);
            }
        }
#pragma unroll
        for (int h = 0; h < 3; h++) m[h] = wave_max64(m[h]);
        float s[3] = {0.f, 0.f, 0.f};
        for (int i = lane; i < deg; i += 64) {
            int sv = srcv[edge_list[s0 + i]];
            float4 elv = el[sv];
            float vv[3] = {elv.x, elv.y, elv.z};
#pragma unroll
            for (int h = 0; h < 3; h++) {
                float v = vv[h] + ern[h];
                v = v > 0.f ? v : NEG_SLOPE * v;
                s[h] += __expf(v - m[h]);
            }
        }
#pragma unroll
        for (int h = 0; h < 3; h++) s[h] = 1.f / (wave_sum64(s[h]) + 1e-16f);
        constexpr int NC = (HD + 63) / 64;
        float acc[NC];
#pragma unroll
        for (int j = 0; j < NC; j++) acc[j] = 0.f;
        for (int i = 0; i < deg; i++) {
            int sv = srcv[edge_list[s0 + i]];
            float4 elv = el[sv];
            float vv[3] = {elv.x, elv.y, elv.z};
            float a[3];
#pragma unroll
            for (int h = 0; h < 3; h++) {
                float v = vv[h] + ern[h];
                v = v > 0.f ? v : NEG_SLOPE * v;
                a[h] = __expf(v - m[h]) * s[h];
            }
            const float* zr = z + (size_t)sv * HD;
#pragma unroll
            for (int j = 0; j < NC; j++) {
                int c = lane + 64 * j;
                if (c < HD) acc[j] += a[c / D] * zr[c];
            }
        }
#pragma unroll
        for (int j = 0; j < NC; j++) {
            int c = lane + 64 * j;
            if (c < HD) orow[c] = fmaxf(acc[j], 0.f);
        }
    }
}

// ---------------- Layer 2 GEMM: z2 = x1 @ W2 (50000x96 @ 96x192), fused el2/er2 ----------------

__global__ __launch_bounds__(256) void k_gemm2(const float* __restrict__ A,
                                               const float* __restrict__ B,
                                               const float* __restrict__ al,
                                               const float* __restrict__ ar,
                                               float* __restrict__ C,
                                               float* __restrict__ el2,
                                               float* __restrict__ er2, int M) {
    __shared__ float sA[64][17];
    __shared__ float sB[16][64];
    int t = threadIdx.x;
    int n0 = blockIdx.x * 64;
    int h = blockIdx.y;       // head: columns c0..c0+63
    int c0 = h * 64;
    int ty = t >> 4, tx = t & 15;
    float acc[4][4] = {};
    for (int k0 = 0; k0 < 96; k0 += 16) {
        int arow = t >> 2, aq = (t & 3) * 4;
        float4 av = make_float4(0.f, 0.f, 0.f, 0.f);
        if (n0 + arow < M)
            av = *reinterpret_cast<const float4*>(&A[(size_t)(n0 + arow) * 96 + k0 + aq]);
        sA[arow][aq + 0] = av.x; sA[arow][aq + 1] = av.y;
        sA[arow][aq + 2] = av.z; sA[arow][aq + 3] = av.w;
        int brow = t >> 4, bq = (t & 15) * 4;
        float4 bv = *reinterpret_cast<const float4*>(&B[(size_t)(k0 + brow) * 192 + c0 + bq]);
        *reinterpret_cast<float4*>(&sB[brow][bq]) = bv;
        __syncthreads();
#pragma unroll
        for (int kk = 0; kk < 16; kk++) {
            float a[4];
#pragma unroll
            for (int i = 0; i < 4; i++) a[i] = sA[ty * 4 + i][kk];
            float4 bb = *reinterpret_cast<const float4*>(&sB[kk][tx * 4]);
            float b[4] = {bb.x, bb.y, bb.z, bb.w};
#pragma unroll
            for (int i = 0; i < 4; i++)
#pragma unroll
                for (int j = 0; j < 4; j++) acc[i][j] += a[i] * b[j];
        }
        __syncthreads();
    }
    float alv[4], arv[4];
#pragma unroll
    for (int j = 0; j < 4; j++) {
        alv[j] = al[c0 + tx * 4 + j];
        arv[j] = ar[c0 + tx * 4 + j];
    }
#pragma unroll
    for (int i = 0; i < 4; i++) {
        int r = n0 + ty * 4 + i;
        float pl = 0.f, pr = 0.f;
#pragma unroll
        for (int j = 0; j < 4; j++) { pl += acc[i][j] * alv[j]; pr += acc[i][j] * arv[j]; }
        // reduce across the 16 tx lanes (same ty group)
#pragma unroll
        for (int o = 1; o < 16; o <<= 1) { pl += __shfl_xor(pl, o); pr += __shfl_xor(pr, o); }
        if (r < M) {
            float4 o4 = make_float4(acc[i][0], acc[i][1], acc[i][2], acc[i][3]);
            *reinterpret_cast<float4*>(&C[(size_t)r * 192 + c0 + tx * 4]) = o4;
            if (tx == 0) { el2[r * 4 + h] = pl; er2[r * 4 + h] = pr; }
        }
    }
}

// ---------------- graph mean-pool (graph_ids sorted) ----------------

__global__ __launch_bounds__(192) void k_pool(const float* __restrict__ x2,
                                              const int* __restrict__ gid,
                                              float* __restrict__ gsum,
                                              int* __restrict__ gcnt, int n) {
    int base = blockIdx.x * 128;
    if (base >= n) return;
    int end = base + 128; if (end > n) end = n;
    int c = threadIdx.x;
    float acc = 0.f;
    int gprev = gid[base];
    for (int i = base; i < end; i++) {
        int g = gid[i];
        if (g != gprev) {
            atomicAdd(&gsum[gprev * 192 + c], acc);
            acc = 0.f;
            gprev = g;
        }
        acc += x2[(size_t)i * 192 + c];
    }
    atomicAdd(&gsum[gprev * 192 + c], acc);
    if (c == 0) {
        int cnt = 0;
        gprev = gid[base];
        for (int i = base; i < end; i++) {
            int g = gid[i];
            if (g != gprev) { atomicAdd(&gcnt[gprev], cnt); cnt = 0; gprev = g; }
            cnt++;
        }
        atomicAdd(&gcnt[gprev], cnt);
    }
}

// ---------------- MLP head: one wave per graph ----------------

__global__ __launch_bounds__(64) void k_head(const float* __restrict__ gsum,
                                             const int* __restrict__ gcnt,
                                             const float* __restrict__ d1w,
                                             const float* __restrict__ d1b,
                                             const float* __restrict__ d2w,
                                             const float* __restrict__ d2b,
                                             float* __restrict__ out, int G) {
    int g = blockIdx.x, j = threadIdx.x;
    float inv = 1.f / fmaxf((float)gcnt[g], 1.f);
    float h = d1b[j];
    for (int k = 0; k < 192; k++) h += (gsum[g * 192 + k] * inv) * d1w[(size_t)k * 64 + j];
    h = fmaxf(h, 0.f);
    float v = h * d2w[j];
    for (int off = 32; off; off >>= 1) v += __shfl_xor(v, off);
    if (j == 0) out[g] = v + d2b[0];
}

// ---------------- launch ----------------

extern "C" void kernel_launch(void* const* d_in, const int* in_sizes, int n_in,
                              void* d_out, int out_size, void* d_ws, size_t ws_size,
                              hipStream_t stream) {
    const float* feat = (const float*)d_in[0];
    const int* src = (const int*)d_in[1];
    const int* dst = (const int*)d_in[2];
    const int* gid = (const int*)d_in[3];
    const float* W1 = (const float*)d_in[4];
    const float* al1 = (const float*)d_in[5];
    const float* ar1 = (const float*)d_in[6];
    const float* W2 = (const float*)d_in[7];
    const float* al2 = (const float*)d_in[8];
    const float* ar2 = (const float*)d_in[9];
    const float* d1w = (const float*)d_in[10];
    const float* d1b = (const float*)d_in[11];
    const float* d2w = (const float*)d_in[12];
    const float* d2b = (const float*)d_in[13];
    float* out = (float*)d_out;
    const int N = in_sizes[0] / 10;   // 50000
    const int E = in_sizes[1];        // 800000
    const int G = out_size;           // 128

    char* p = (char*)d_ws;
    auto take = [&](size_t bytes) -> char* {
        char* r = p;
        p += (bytes + 255) & ~(size_t)255;
        return r;
    };
    float* region0 = (float*)take((size_t)N * 192 * 4);  // z1+x1, later x2
    float* z1 = region0;
    float* x1 = region0 + (size_t)N * 96;
    float* x2 = region0;
    float* z2 = (float*)take((size_t)N * 192 * 4);
    float4* el1 = (float4*)take((size_t)N * 16);
    float4* er1 = (float4*)take((size_t)N * 16);
    float* el2 = (float*)take((size_t)N * 16);
    float* er2 = (float*)take((size_t)N * 16);
    int* deg = (int*)take((size_t)N * 4);
    int* row_start = (int*)take((size_t)(N + 1) * 4);
    int* cursor = (int*)take((size_t)N * 4);
    int* edge_list = (int*)take((size_t)E * 4);
    float* gsum = (float*)take((size_t)G * 192 * 4);
    int* gcnt = (int*)take((size_t)G * 4);

    hipMemsetAsync(deg, 0, (size_t)N * 4, stream);
    hipMemsetAsync(cursor, 0, (size_t)N * 4, stream);
    hipMemsetAsync(gsum, 0, (size_t)G * 192 * 4, stream);
    hipMemsetAsync(gcnt, 0, (size_t)G * 4, stream);

    // CSR build (bucket edges by dst)
    k_hist<<<(E + 255) / 256, 256, 0, stream>>>(dst, deg, E);
    k_scan<<<1, 1024, 0, stream>>>(deg, row_start, N);
    k_scatter<<<(E + 255) / 256, 256, 0, stream>>>(dst, row_start, cursor, edge_list, E);

    // Layer 1
    k_gemm1<<<(N + 255) / 256, 256, 0, stream>>>(feat, W1, al1, ar1, z1, el1, er1, N);
    k_agg<32, 2><<<((size_t)N * 64 + 255) / 256, 256, 0, stream>>>(
        z1, el1, er1, row_start, edge_list, src, x1, N);
    // Layer 2 (el2/er2 fused into GEMM epilogue)
    k_gemm2<<<dim3((N + 63) / 64, 3), 256, 0, stream>>>(x1, W2, al2, ar2, z2, el2, er2, N);
    k_agg<64, 4><<<((size_t)N * 64 + 255) / 256, 256, 0, stream>>>(
        z2, (const float4*)el2, (const float4*)er2, row_start, edge_list, src, x2, N);
    // Pool + head
    k_pool<<<(N + 127) / 128, 192, 0, stream>>>(x2, gid, gsum, gcnt, N);
    k_head<<<G, 64, 0, stream>>>(gsum, gcnt, d1w, d1b, d2w, d2b, out, G);
}